// Round 1
// baseline (233.415 us; speedup 1.0000x reference)
//
#include <hip/hip_runtime.h>

// SPGG Fermi update, L=4096 periodic lattice.
// out[i,j] = adopt ? t[neighbor(dir)] : t, adopt = lp <= 1/(1+exp((P_i - P_n)/0.1))
// P = (t==1 ? c5 : d5), c5/d5 = 5-point sums of per-site payoff values,
// replicated in the reference's exact f32 op order.

#define LSZ 4096
#define LMASK 4095

__global__ __launch_bounds__(256) void spgg_fermi_kernel(
    const float* __restrict__ t,       // type matrix, 0.0/1.0
    const float* __restrict__ lp,      // learning probabilities
    const int*   __restrict__ dir,     // learning direction 0..3
    float* __restrict__ out)
{
    // 32x32 output tile, halo radius 3.
    __shared__ float c_s[38][40];   // t values, rows by-3..by+34, cols bx-3..bx+34
    __shared__ float a_s[36][40];   // per-site payoff base a = (coop_num/5)*3, offsets 1..36
    __shared__ float p_s[34][40];   // profit, offsets 2..35

    const int bx = blockIdx.x * 32;   // global col base of output tile
    const int by = blockIdx.y * 32;   // global row base
    const int tid = threadIdx.y * 32 + threadIdx.x;

    // ---- stage t tile (38x38 with wrap) ----
    for (int idx = tid; idx < 38 * 38; idx += 256) {
        int r  = idx / 38;
        int cc = idx - r * 38;
        int gr = (by + r - 3) & LMASK;
        int gc = (bx + cc - 3) & LMASK;
        c_s[r][cc] = t[gr * LSZ + gc];
    }
    __syncthreads();

    // ---- a = (coop_num / 5) * 3 over the 36x36 interior (c-coords 1..36) ----
    for (int idx = tid; idx < 36 * 36; idx += 256) {
        int r  = idx / 36 + 1;
        int cc = idx - (r - 1) * 36 + 1;
        // reference order: center + up + down + left + right (exact small ints)
        float n1 = (((c_s[r][cc] + c_s[r - 1][cc]) + c_s[r + 1][cc])
                    + c_s[r][cc - 1]) + c_s[r][cc + 1];
        a_s[r - 1][cc - 1] = n1 / 5.0f * 3.0f;
    }
    __syncthreads();

    // ---- profit over 34x34 (c-coords 2..35) ----
    for (int idx = tid; idx < 34 * 34; idx += 256) {
        int r  = idx / 34 + 2;
        int cc = idx - (r - 2) * 34 + 2;
        float ac = a_s[r - 1][cc - 1];
        float au = a_s[r - 2][cc - 1];
        float ad = a_s[r    ][cc - 1];
        float al = a_s[r - 1][cc - 2];
        float ar = a_s[r - 1][cc    ];
        // d5: sum of a in reference order; c5: sum of (a-1) — (a-1) is exact.
        float d5 = (((ac + au) + ad) + al) + ar;
        float c5 = (((((ac - 1.0f) + (au - 1.0f)) + (ad - 1.0f))
                     + (al - 1.0f)) + (ar - 1.0f));
        p_s[r - 2][cc - 2] = (c_s[r][cc] == 1.0f) ? c5 : d5;
    }
    __syncthreads();

    // ---- Fermi decision on the 32x32 inner tile (c-coords 3..34) ----
    for (int yy = threadIdx.y; yy < 32; yy += 8) {
        int r  = yy + 3;
        int cc = threadIdx.x + 3;
        int gr = by + yy;
        int gc = bx + threadIdx.x;
        int gidx = gr * LSZ + gc;

        int k = dir[gidx];
        // k=0: left (j-1), k=1: right (j+1), k=2: up (i-1), k=3: down (i+1)
        int nr = r + ((k == 2) ? -1 : (k == 3) ? 1 : 0);
        int nc = cc + ((k == 0) ? -1 : (k == 1) ? 1 : 0);

        float pc = p_s[r - 2][cc - 2];
        float pn = p_s[nr - 2][nc - 2];
        float arg = (pc - pn) / 0.1f;            // f32 IEEE div, matches ref
        float e = (float)exp((double)arg);       // correctly-rounded f32 exp
        float W = 1.0f / (1.0f + e);

        float tc = c_s[r][cc];
        float tn = c_s[nr][nc];
        out[gidx] = (lp[gidx] <= W) ? tn : tc;
    }
}

extern "C" void kernel_launch(void* const* d_in, const int* in_sizes, int n_in,
                              void* d_out, int out_size, void* d_ws, size_t ws_size,
                              hipStream_t stream)
{
    const float* t   = (const float*)d_in[0];
    const float* lp  = (const float*)d_in[1];
    const int*   dir = (const int*)d_in[2];
    float* out = (float*)d_out;

    dim3 grid(LSZ / 32, LSZ / 32);   // 128 x 128 blocks
    dim3 block(32, 8);
    hipLaunchKernelGGL(spgg_fermi_kernel, grid, block, 0, stream, t, lp, dir, out);
}